// Round 5
// baseline (156.897 us; speedup 1.0000x reference)
//
#include <hip/hip_runtime.h>

// pred (B,C,S) f32, labels (B,S) int32, scalar f32 out.
constexpr int   Bn    = 512;
constexpr int   Cn    = 4;
constexpr int   Sn    = 16384;
constexpr int   PADv  = 3;
constexpr float Qv    = 0.7f;
constexpr int   BPB   = 8;            // blocks per batch (R2's best-measured grid)
constexpr int   CHUNK = Sn / BPB;     // 2048 positions per block
constexpr int   NBLK  = Bn * BPB;     // 4096 blocks
constexpr int   HB    = BPB / 2;      // 4 lower-half blocks, never pad (lengths >= S/2)

// ws layout: float psum[NBLK]; int pcnt[Bn*HB]; int ticket[1]
// psum/pcnt fully rewritten each call (atomic stores); ticket memset per call.

__device__ __forceinline__ float gce_raw(float l0, float l1, float l2, int lb)
{
    const float m   = fmaxf(fmaxf(l0, l1), l2);
    const float e0  = __expf(l0 - m);
    const float e1  = __expf(l1 - m);
    const float e2  = __expf(l2 - m);
    const float inv = 1.0f / (e0 + e1 + e2);
    const int   c   = min(max(lb, 0), 2);          // safe_lab
    float pt = ((c == 0) ? e0 : (c == 1) ? e1 : e2) * inv;
    pt = fminf(fmaxf(pt, 1e-7f), 1.0f);            // clip(probs)
    return 1.0f - __expf(Qv * __logf(pt));         // 1 - pt^Q  (pt >= 1e-7)
}

// ---------------------------------------------------------------------------
// Single fused kernel. Main loop identical to R2 (best measured). Each block
// publishes (psum, pcnt) with agent-scope atomic stores, takes a ticket; the
// last block inline-reduces all partials (agent-scope atomic loads -> immune
// to stale per-XCD L2 across graph replays) and writes the scalar.
// mask = (label != PAD): PAD is a contiguous suffix => mask == (s < j),
// j = 8192 + count(non-pad upper). Lower half (s < 8192 <= length): no mask.
// ---------------------------------------------------------------------------
__global__ __launch_bounds__(256) void gce_fused(
    const float* __restrict__ pred, const int* __restrict__ labels,
    float* psum, int* pcnt, int* ticket, float* __restrict__ out)
{
    const int bid = blockIdx.x;
    const int b   = bid >> 3;
    const int blk = bid & (BPB - 1);
    const int t   = threadIdx.x;
    const int s0  = blk * CHUNK;

    const float4* p0  = reinterpret_cast<const float4*>(pred + ((size_t)b * Cn + 0) * Sn);
    const float4* p1  = reinterpret_cast<const float4*>(pred + ((size_t)b * Cn + 1) * Sn);
    const float4* p2  = reinterpret_cast<const float4*>(pred + ((size_t)b * Cn + 2) * Sn);
    const int4*   lab = reinterpret_cast<const int4*>(labels + (size_t)b * Sn);

    const int vi0 = (s0 >> 2) + t;            // sub-iter 0
    const int vi1 = vi0 + 256;                // sub-iter 1

    float acc = 0.0f;
    int   cnt = 0;

    if (blk < HB) {
        // s < S/2: never pad. Unconditional, no mask, no count.
        const int4   lv0 = lab[vi0];
        const int4   lv1 = lab[vi1];
        const float4 a0 = p0[vi0], u0 = p1[vi0], v0 = p2[vi0];
        const float4 a1 = p0[vi1], u1 = p1[vi1], v1 = p2[vi1];
        acc += gce_raw(a0.x, u0.x, v0.x, lv0.x);
        acc += gce_raw(a0.y, u0.y, v0.y, lv0.y);
        acc += gce_raw(a0.z, u0.z, v0.z, lv0.z);
        acc += gce_raw(a0.w, u0.w, v0.w, lv0.w);
        acc += gce_raw(a1.x, u1.x, v1.x, lv1.x);
        acc += gce_raw(a1.y, u1.y, v1.y, lv1.y);
        acc += gce_raw(a1.z, u1.z, v1.z, lv1.z);
        acc += gce_raw(a1.w, u1.w, v1.w, lv1.w);
    } else {
        const int4 lv0 = lab[vi0];
        const int4 lv1 = lab[vi1];
        const bool ap0 = (lv0.x == PADv) & (lv0.y == PADv) &
                         (lv0.z == PADv) & (lv0.w == PADv);
        const bool ap1 = (lv1.x == PADv) & (lv1.y == PADv) &
                         (lv1.z == PADv) & (lv1.w == PADv);
        const bool go0 = !__all(ap0);
        const bool go1 = !__all(ap1);
        auto proc4 = [&](const int4& lv, const float4& x0, const float4& x1,
                         const float4& x2) {
            const float g0 = gce_raw(x0.x, x1.x, x2.x, lv.x);
            const float g1 = gce_raw(x0.y, x1.y, x2.y, lv.y);
            const float g2 = gce_raw(x0.z, x1.z, x2.z, lv.z);
            const float g3 = gce_raw(x0.w, x1.w, x2.w, lv.w);
            if (lv.x != PADv) { acc += g0; ++cnt; }
            if (lv.y != PADv) { acc += g1; ++cnt; }
            if (lv.z != PADv) { acc += g2; ++cnt; }
            if (lv.w != PADv) { acc += g3; ++cnt; }
        };
        if (go0) { proc4(lv0, p0[vi0], p1[vi0], p2[vi0]); }
        if (go1) { proc4(lv1, p0[vi1], p1[vi1], p2[vi1]); }
    }

    // ---- block-wide reduce ---------------------------------------------
    #pragma unroll
    for (int off = 32; off > 0; off >>= 1) {
        acc += __shfl_down(acc, off, 64);
        cnt += __shfl_down(cnt, off, 64);
    }
    __shared__ float wsum[4];
    __shared__ int   wcnt[4];
    if ((t & 63) == 0) { wsum[t >> 6] = acc; wcnt[t >> 6] = cnt; }
    __syncthreads();

    __shared__ int fin;
    if (t == 0) {
        const float total = wsum[0] + wsum[1] + wsum[2] + wsum[3];
        __hip_atomic_store(&psum[bid], total, __ATOMIC_RELAXED, __HIP_MEMORY_SCOPE_AGENT);
        if (blk >= HB) {
            const int ctot = wcnt[0] + wcnt[1] + wcnt[2] + wcnt[3];
            __hip_atomic_store(&pcnt[b * HB + (blk - HB)], ctot,
                               __ATOMIC_RELAXED, __HIP_MEMORY_SCOPE_AGENT);
        }
        const int old = __hip_atomic_fetch_add(ticket, 1, __ATOMIC_ACQ_REL,
                                               __HIP_MEMORY_SCOPE_AGENT);
        fin = (old == NBLK - 1);
    }
    __syncthreads();
    if (!fin) return;

    // ---- inline finisher (last block only) ------------------------------
    float facc = 0.0f;
    for (int b2 = t; b2 < Bn; b2 += 256) {
        float s = 0.0f;
        int   c = CHUNK * HB;                 // 8192 from the never-pad lower half
        #pragma unroll
        for (int k = 0; k < BPB; ++k)
            s += __hip_atomic_load(&psum[b2 * BPB + k],
                                   __ATOMIC_RELAXED, __HIP_MEMORY_SCOPE_AGENT);
        #pragma unroll
        for (int k = 0; k < HB; ++k)
            c += __hip_atomic_load(&pcnt[b2 * HB + k],
                                   __ATOMIC_RELAXED, __HIP_MEMORY_SCOPE_AGENT);
        // c == j (first PAD). c == Sn impossible here (lengths <= S-1).
        facc += s / (Qv * (float)c);
    }
    #pragma unroll
    for (int off = 32; off > 0; off >>= 1) facc += __shfl_down(facc, off, 64);
    __shared__ float fw[4];
    if ((t & 63) == 0) fw[t >> 6] = facc;
    __syncthreads();
    if (t == 0) out[0] = (fw[0] + fw[1] + fw[2] + fw[3]) / (float)Bn;
}

// ---------------------------------------------------------------------------
extern "C" void kernel_launch(void* const* d_in, const int* in_sizes, int n_in,
                              void* d_out, int out_size, void* d_ws, size_t ws_size,
                              hipStream_t stream)
{
    const float* pred   = (const float*)d_in[0];
    const int*   labels = (const int*)d_in[1];
    float*       out    = (float*)d_out;

    float* psum   = (float*)d_ws;                 // 4096 f32
    int*   pcnt   = (int*)(psum + NBLK);          // 2048 i32
    int*   ticket = (int*)(pcnt + Bn * HB);       // 1 i32

    hipMemsetAsync(ticket, 0, sizeof(int), stream);
    hipLaunchKernelGGL(gce_fused, dim3(NBLK), dim3(256), 0, stream,
                       pred, labels, psum, pcnt, ticket, out);
}

// Round 6
// 26.452 us; speedup vs baseline: 5.9314x; 5.9314x over previous
//
#include <hip/hip_runtime.h>

// pred (B,C,S) f32, labels (B,S) int32, scalar f32 out.
constexpr int   Bn    = 512;
constexpr int   Cn    = 4;
constexpr int   Sn    = 16384;
constexpr int   PADv  = 3;
constexpr float Qv    = 0.7f;
constexpr int   QPB   = 4;             // quarter-units per half-row
constexpr int   UNIT  = 2048;          // positions per unit (2 sub-iters of 1024)
constexpr int   NBLK  = Bn * QPB;      // 2048 blocks: one lower + one upper unit each

// ws layout: float psum[NBLK]; int pcnt[NBLK]
// Fully rewritten by gce_main each call (no init needed); finisher kernel
// launch is the coherence point (NO per-block agent-scope acq_rel — R5 showed
// that forces per-block L2 writeback/invalidate on gfx950 and serialized
// everything, 157us).

__device__ __forceinline__ float gce_raw(float l0, float l1, float l2, int lb)
{
    const float m   = fmaxf(fmaxf(l0, l1), l2);
    const float e0  = __expf(l0 - m);
    const float e1  = __expf(l1 - m);
    const float e2  = __expf(l2 - m);
    const float inv = 1.0f / (e0 + e1 + e2);
    const int   c   = min(max(lb, 0), 2);          // safe_lab
    float pt = ((c == 0) ? e0 : (c == 1) ? e1 : e2) * inv;
    pt = fminf(fmaxf(pt, 1e-7f), 1.0f);            // clip(probs)
    return 1.0f - __expf(Qv * __logf(pt));         // 1 - pt^Q  (pt >= 1e-7)
}

// ---------------------------------------------------------------------------
// Balanced main pass: block (b,q) handles lower unit q (s in [q*2048,
// q*2048+2048), never pad since lengths >= S/2: unconditional, uncounted)
// and upper unit q (s in [8192+q*2048, ...): __all-gated, label-masked,
// counted). Every block: 2 + (0..2) iterations -> near-uniform lifetime,
// 8 blocks/CU in a single generation. mask = (label != PAD) == (s < j);
// j = 8192 + count(non-pad upper).
// ---------------------------------------------------------------------------
__global__ __launch_bounds__(256, 8) void gce_main(
    const float* __restrict__ pred, const int* __restrict__ labels,
    float* __restrict__ psum, int* __restrict__ pcnt)
{
    const int i = blockIdx.x;
    const int b = i >> 2;              // / QPB
    const int q = i & (QPB - 1);
    const int t = threadIdx.x;

    const float4* p0  = reinterpret_cast<const float4*>(pred + ((size_t)b * Cn + 0) * Sn);
    const float4* p1  = reinterpret_cast<const float4*>(pred + ((size_t)b * Cn + 1) * Sn);
    const float4* p2  = reinterpret_cast<const float4*>(pred + ((size_t)b * Cn + 2) * Sn);
    const int4*   lab = reinterpret_cast<const int4*>(labels + (size_t)b * Sn);

    const int viL = ((q * UNIT) >> 2) + t;            // lower unit, sub-iter 0
    const int viU = ((Sn / 2 + q * UNIT) >> 2) + t;   // upper unit, sub-iter 0

    // All label vectors up front: one vmcnt epoch covers gates + lower compute.
    const int4 lvL0 = lab[viL];
    const int4 lvL1 = lab[viL + 256];
    const int4 lvU0 = lab[viU];
    const int4 lvU1 = lab[viU + 256];
    const float4 aL0 = p0[viL],       uL0 = p1[viL],       vL0 = p2[viL];
    const float4 aL1 = p0[viL + 256], uL1 = p1[viL + 256], vL1 = p2[viL + 256];

    const bool ap0 = (lvU0.x == PADv) & (lvU0.y == PADv) &
                     (lvU0.z == PADv) & (lvU0.w == PADv);
    const bool ap1 = (lvU1.x == PADv) & (lvU1.y == PADv) &
                     (lvU1.z == PADv) & (lvU1.w == PADv);
    const bool go0 = !__all(ap0);
    const bool go1 = !__all(ap1);

    float acc = 0.0f;
    int   cnt = 0;

    // Lower: unconditional, no mask, no count (s < S/2 <= length).
    acc += gce_raw(aL0.x, uL0.x, vL0.x, lvL0.x);
    acc += gce_raw(aL0.y, uL0.y, vL0.y, lvL0.y);
    acc += gce_raw(aL0.z, uL0.z, vL0.z, lvL0.z);
    acc += gce_raw(aL0.w, uL0.w, vL0.w, lvL0.w);
    acc += gce_raw(aL1.x, uL1.x, vL1.x, lvL1.x);
    acc += gce_raw(aL1.y, uL1.y, vL1.y, lvL1.y);
    acc += gce_raw(aL1.z, uL1.z, vL1.z, lvL1.z);
    acc += gce_raw(aL1.w, uL1.w, vL1.w, lvL1.w);

    // Upper: gated loads, masked + counted accumulation.
    auto proc4 = [&](const int4& lv, const float4& x0, const float4& x1,
                     const float4& x2) {
        const float g0 = gce_raw(x0.x, x1.x, x2.x, lv.x);
        const float g1 = gce_raw(x0.y, x1.y, x2.y, lv.y);
        const float g2 = gce_raw(x0.z, x1.z, x2.z, lv.z);
        const float g3 = gce_raw(x0.w, x1.w, x2.w, lv.w);
        if (lv.x != PADv) { acc += g0; ++cnt; }
        if (lv.y != PADv) { acc += g1; ++cnt; }
        if (lv.z != PADv) { acc += g2; ++cnt; }
        if (lv.w != PADv) { acc += g3; ++cnt; }
    };
    if (go0) proc4(lvU0, p0[viU],       p1[viU],       p2[viU]);
    if (go1) proc4(lvU1, p0[viU + 256], p1[viU + 256], p2[viU + 256]);

    // Block-wide reduce: 64-lane shuffle, then across 4 waves via LDS.
    #pragma unroll
    for (int off = 32; off > 0; off >>= 1) {
        acc += __shfl_down(acc, off, 64);
        cnt += __shfl_down(cnt, off, 64);
    }
    __shared__ float wsum[4];
    __shared__ int   wcnt[4];
    if ((t & 63) == 0) { wsum[t >> 6] = acc; wcnt[t >> 6] = cnt; }
    __syncthreads();
    if (t == 0) {
        psum[i] = wsum[0] + wsum[1] + wsum[2] + wsum[3];
        pcnt[i] = wcnt[0] + wcnt[1] + wcnt[2] + wcnt[3];
    }
}

// ---------------------------------------------------------------------------
// Finisher: one block combines 2048 partials -> scalar mean.
// ---------------------------------------------------------------------------
__global__ __launch_bounds__(256) void gce_final(
    const float* __restrict__ psum, const int* __restrict__ pcnt,
    float* __restrict__ out)
{
    const int t = threadIdx.x;
    float acc = 0.0f;
    for (int b = t; b < Bn; b += 256) {
        float s = 0.0f;
        int   c = Sn / 2;                 // lower half always counts fully
        #pragma unroll
        for (int k = 0; k < QPB; ++k) {
            s += psum[b * QPB + k];
            c += pcnt[b * QPB + k];
        }
        // c == j = first PAD index (there is always >=1 pad: lengths <= S-1).
        acc += s / (Qv * (float)c);
    }
    #pragma unroll
    for (int off = 32; off > 0; off >>= 1) acc += __shfl_down(acc, off, 64);
    __shared__ float w[4];
    if ((t & 63) == 0) w[t >> 6] = acc;
    __syncthreads();
    if (t == 0) out[0] = (w[0] + w[1] + w[2] + w[3]) / (float)Bn;
}

// ---------------------------------------------------------------------------
extern "C" void kernel_launch(void* const* d_in, const int* in_sizes, int n_in,
                              void* d_out, int out_size, void* d_ws, size_t ws_size,
                              hipStream_t stream)
{
    const float* pred   = (const float*)d_in[0];
    const int*   labels = (const int*)d_in[1];
    float*       out    = (float*)d_out;

    float* psum = (float*)d_ws;            // 2048 f32
    int*   pcnt = (int*)(psum + NBLK);     // 2048 i32

    hipLaunchKernelGGL(gce_main, dim3(NBLK), dim3(256), 0, stream,
                       pred, labels, psum, pcnt);
    hipLaunchKernelGGL(gce_final, dim3(1), dim3(256), 0, stream,
                       psum, pcnt, out);
}